// Round 10
// baseline (233.170 us; speedup 1.0000x reference)
//
#include <hip/hip_runtime.h>

// UniformBottomUpHTMM: T=64 trees, depth 10 (N1=2047, heap layout), C=16,
// M=64, G=16. SINGLE kernel, NO workspace, NO cross-block sync.
// 1024 blocks = (g,t), bid = g*64+t so all 16 g-blocks of a tree share an
// XCD (bid%8 == t%8) and the redundant x/inv_map re-reads hit that XCD's L2.
// Each block: computes softmax(A,B,Pi) itself (redundant but ~0.5us, parallel),
// gathers its tree's 2047 symbols in two latency epochs, then runs the whole
// bottom-up pass in LDS. Only the (64,16) ll sums leave the chip.
//
// r8/r9 lesson: both atomic-RMW and store-flag device barriers stall the
// resident grid ~125us (windows identical at ~145us, VALUBusy 11%); this
// removes the barrier and d_ws entirely as the discriminating experiment.

#define C_DIM 16
#define M_DIM 64
#define G_DIM 16
#define T_TREES 64
#define N1 2047

__global__ __launch_bounds__(256, 4) void htmm_kernel(
    const int* __restrict__ x,
    const int* __restrict__ inv_map,
    const float* __restrict__ lA,
    const float* __restrict__ lB,
    const float* __restrict__ lPi,
    float* __restrict__ out)
{
    const int g   = blockIdx.x >> 6;           // 0..15
    const int t   = blockIdx.x & (T_TREES-1);  // 0..63 ; bid%8 == t%8
    const int tid = threadIdx.x;

    __shared__ __align__(16) float sA[C_DIM * C_DIM];   // softmax_i A[i,j,g]
    __shared__ __align__(16) float sB[C_DIM * M_DIM];   // softmax_m B[c,m,g]
    __shared__ __align__(16) float sPB[C_DIM * M_DIM];  // Pi[c]*B[c,m]
    __shared__ __align__(16) float sPi[C_DIM];
    __shared__ __align__(16) unsigned char xs[2048];
    __shared__ float buf0[C_DIM * 256];   // L8 betas (SoA stride 256)
    __shared__ float buf1[C_DIM * 128];
    __shared__ float wsum[4];

    const int base = t * N1;

    // ---- Phase A0: issue independent global loads (epoch 1) ----
    int iv[8];
    #pragma unroll
    for (int k = 0; k < 8; ++k) {
        int i = tid + 256 * k;
        iv[k] = inv_map[base + (i < N1 ? i : 0)];
    }
    const int jA = tid >> 4, iA = tid & 15;
    float vA = lA[(iA * C_DIM + jA) * G_DIM + g];
    const int cB = tid >> 4, l16 = tid & 15;
    float e0 = lB[(cB * M_DIM + l16 +  0) * G_DIM + g];
    float e1 = lB[(cB * M_DIM + l16 + 16) * G_DIM + g];
    float e2 = lB[(cB * M_DIM + l16 + 32) * G_DIM + g];
    float e3 = lB[(cB * M_DIM + l16 + 48) * G_DIM + g];
    float vPi = lPi[(tid & 15) * G_DIM + g];

    // ---- dependent gather (epoch 2) overlapped with softmax math ----
    int xv8[8];
    #pragma unroll
    for (int k = 0; k < 8; ++k) xv8[k] = x[iv[k]];

    {   // A: softmax over i within each column jA
        float mx = vA;
        #pragma unroll
        for (int m = 1; m < 16; m <<= 1) mx = fmaxf(mx, __shfl_xor(mx, m, 16));
        float e = __expf(vA - mx);
        float s = e;
        #pragma unroll
        for (int m = 1; m < 16; m <<= 1) s += __shfl_xor(s, m, 16);
        sA[iA * C_DIM + jA] = e / s;
    }
    {   // B: softmax over m within row cB (4 symbols per lane)
        float mx = fmaxf(fmaxf(e0, e1), fmaxf(e2, e3));
        #pragma unroll
        for (int m = 1; m < 16; m <<= 1) mx = fmaxf(mx, __shfl_xor(mx, m, 16));
        e0 = __expf(e0 - mx); e1 = __expf(e1 - mx);
        e2 = __expf(e2 - mx); e3 = __expf(e3 - mx);
        float s = e0 + e1 + e2 + e3;
        #pragma unroll
        for (int m = 1; m < 16; m <<= 1) s += __shfl_xor(s, m, 16);
        float inv = 1.f / s;
        sB[cB * M_DIM + l16 +  0] = e0 * inv;
        sB[cB * M_DIM + l16 + 16] = e1 * inv;
        sB[cB * M_DIM + l16 + 32] = e2 * inv;
        sB[cB * M_DIM + l16 + 48] = e3 * inv;
    }
    {   // Pi: softmax over c (every 16-lane group computes it; same result)
        float mx = vPi;
        #pragma unroll
        for (int m = 1; m < 16; m <<= 1) mx = fmaxf(mx, __shfl_xor(mx, m, 16));
        float e = __expf(vPi - mx);
        float s = e;
        #pragma unroll
        for (int m = 1; m < 16; m <<= 1) s += __shfl_xor(s, m, 16);
        if (tid < C_DIM) sPi[tid] = e / s;
    }
    #pragma unroll
    for (int k = 0; k < 8; ++k) {
        int i = tid + 256 * k;
        if (i < N1) xs[i] = (unsigned char)xv8[k];
    }
    __syncthreads();

    // ---- sPB = Pi[c] * B[c][m] (leaf emission, premultiplied) ----
    {
        float pc = sPi[cB];
        sPB[cB * M_DIM + l16 +  0] = pc * sB[cB * M_DIM + l16 +  0];
        sPB[cB * M_DIM + l16 + 16] = pc * sB[cB * M_DIM + l16 + 16];
        sPB[cB * M_DIM + l16 + 32] = pc * sB[cB * M_DIM + l16 + 32];
        sPB[cB * M_DIM + l16 + 48] = pc * sB[cB * M_DIM + l16 + 48];
    }
    __syncthreads();

    float ll = 0.f;

    // ---- fused leaves (L10) + L9 + L8: one L8 node per thread ----
    {
        const int idx = tid;
        const int p8  = 255 + idx;
        float s8[C_DIM];
        #pragma unroll
        for (int k = 0; k < C_DIM; ++k) s8[k] = 0.f;
        #pragma unroll
        for (int c9 = 0; c9 < 2; ++c9) {
            const int p9 = 2 * p8 + 1 + c9;
            float s9[C_DIM];
            #pragma unroll
            for (int k = 0; k < C_DIM; ++k) s9[k] = 0.f;
            #pragma unroll
            for (int cl = 0; cl < 2; ++cl) {
                const int xv = xs[2 * p9 + 1 + cl];
                float b[C_DIM]; float nu = 0.f;
                #pragma unroll
                for (int k = 0; k < C_DIM; ++k) {
                    b[k] = sPB[k * M_DIM + xv];
                    nu += b[k];
                }
                float inv = 0.5f / nu;
                #pragma unroll
                for (int k = 0; k < C_DIM; ++k) s9[k] += b[k] * inv;
                ll += __logf(nu);
            }
            const int xv = xs[p9];
            float bp[C_DIM]; float nu = 0.f;
            #pragma unroll
            for (int i = 0; i < C_DIM; ++i) {
                float ti = 0.f;
                #pragma unroll
                for (int j = 0; j < C_DIM; ++j) ti += sA[i * C_DIM + j] * s9[j];
                bp[i] = ti * sB[i * M_DIM + xv];
                nu += bp[i];
            }
            ll += __logf(nu);
            float inv = 0.5f / nu;
            #pragma unroll
            for (int k = 0; k < C_DIM; ++k) s8[k] += bp[k] * inv;
        }
        const int xv = xs[p8];
        float bp[C_DIM]; float nu = 0.f;
        #pragma unroll
        for (int i = 0; i < C_DIM; ++i) {
            float ti = 0.f;
            #pragma unroll
            for (int j = 0; j < C_DIM; ++j) ti += sA[i * C_DIM + j] * s8[j];
            bp[i] = ti * sB[i * M_DIM + xv];
            nu += bp[i];
        }
        ll += __logf(nu);
        float inv = 1.f / nu;
        #pragma unroll
        for (int k = 0; k < C_DIM; ++k) buf0[k * 256 + idx] = bp[k] * inv;
    }
    __syncthreads();

    // ---- L7: 128 nodes ----
    if (tid < 128) {
        const int idx = tid;
        float s[C_DIM];
        #pragma unroll
        for (int j = 0; j < C_DIM; ++j) {
            float2 cv = ((const float2*)(buf0 + j * 256))[idx];
            s[j] = 0.5f * (cv.x + cv.y);
        }
        const int xv = xs[127 + idx];
        float bp[C_DIM]; float nu = 0.f;
        #pragma unroll
        for (int i = 0; i < C_DIM; ++i) {
            float ti = 0.f;
            #pragma unroll
            for (int j = 0; j < C_DIM; ++j) ti += sA[i * C_DIM + j] * s[j];
            bp[i] = ti * sB[i * M_DIM + xv];
            nu += bp[i];
        }
        ll += __logf(nu);
        float inv = 1.f / nu;
        #pragma unroll
        for (int i = 0; i < C_DIM; ++i) buf1[i * 128 + idx] = bp[i] * inv;
    }
    __syncthreads();

    // ---- L6..L0 (64..1 nodes): wave 0 only, LDS fences not barriers ----
    if (tid < 64) {
        float* cur = buf1; int cs = 128;
        float* nxt = buf0; int ns = 256;
        for (int cnt = 64; cnt >= 1; cnt >>= 1) {
            if (tid < cnt) {
                const int idx = tid;
                float s[C_DIM];
                #pragma unroll
                for (int j = 0; j < C_DIM; ++j) {
                    float a  = cur[j * cs + 2 * idx];
                    float b2 = cur[j * cs + 2 * idx + 1];
                    s[j] = 0.5f * (a + b2);
                }
                const int xv = xs[cnt - 1 + idx];
                float bp[C_DIM]; float nu = 0.f;
                #pragma unroll
                for (int i = 0; i < C_DIM; ++i) {
                    float ti = 0.f;
                    #pragma unroll
                    for (int j = 0; j < C_DIM; ++j) ti += sA[i * C_DIM + j] * s[j];
                    bp[i] = ti * sB[i * M_DIM + xv];
                    nu += bp[i];
                }
                ll += __logf(nu);
                float inv = 1.f / nu;
                #pragma unroll
                for (int i = 0; i < C_DIM; ++i) nxt[i * ns + idx] = bp[i] * inv;
            }
            asm volatile("s_waitcnt lgkmcnt(0)" ::: "memory");
            __builtin_amdgcn_wave_barrier();
            float* tp = cur; cur = nxt; nxt = tp;
            int ts = cs; cs = ns; ns = ts;
        }
    }

    // ---- reduce ll across block ----
    float v = ll;
    #pragma unroll
    for (int off = 32; off > 0; off >>= 1) v += __shfl_down(v, off, 64);
    if ((tid & 63) == 0) wsum[tid >> 6] = v;
    __syncthreads();
    if (tid == 0) out[t * G_DIM + g] = wsum[0] + wsum[1] + wsum[2] + wsum[3];
}

extern "C" void kernel_launch(void* const* d_in, const int* in_sizes, int n_in,
                              void* d_out, int out_size, void* d_ws, size_t ws_size,
                              hipStream_t stream) {
    const int*   x       = (const int*)d_in[0];
    const int*   inv_map = (const int*)d_in[6];
    const float* lA      = (const float*)d_in[7];
    const float* lB      = (const float*)d_in[8];
    const float* lPi     = (const float*)d_in[9];
    float* out = (float*)d_out;

    htmm_kernel<<<dim3(T_TREES * G_DIM), dim3(256), 0, stream>>>(
        x, inv_map, lA, lB, lPi, out);
}

// Round 11
// 216.519 us; speedup vs baseline: 1.0769x; 1.0769x over previous
//
#include <hip/hip_runtime.h>

// UniformBottomUpHTMM: T=64 trees, depth 10 (N1=2047, heap layout), C=16,
// M=64, G=16. SINGLE kernel, 512 blocks, device barrier with NO same-address
// spin hammer:
//   arrival: per-block flag store (distinct words; poison 0xAA..A = not-ready,
//            so no memset/CAS needed - d_ws is re-poisoned before every launch)
//   sweep:   block 0, 256 threads poll 512 distinct flags, s_sleep(32) backoff
//   release: 64 words spaced 64B; 8 blocks poll each word, s_sleep(16) backoff
// r8/r9 lesson: 500 blocks polling ONE word every ~0.13us saturates the
// device coherent point (~145us window, VALUBusy 11%, traffic tiny); r10
// showed no-barrier-but-heavy-traffic is no better. This isolates the spin.

#define C_DIM 16
#define M_DIM 64
#define G_DIM 16
#define T_TREES 64
#define N1 2047

#define PAR_STRIDE 1536
#define XS_BYTE_OFF (G_DIM * PAR_STRIDE * 4)     // 98304
#define BAR_BYTE_OFF (512 * 1024)                // barrier region in d_ws
#define NBLOCKS 512
#define POISON 0xAAAAAAAAu

__global__ __launch_bounds__(256, 2) void htmm_fused(
    const int* __restrict__ x,
    const int* __restrict__ inv_map,
    const float* __restrict__ lA,
    const float* __restrict__ lB,
    const float* __restrict__ lPi,
    float* __restrict__ ws,
    float* __restrict__ out)
{
    const int bid = blockIdx.x;      // 512 blocks, all co-resident (cap >=1024)
    const int tid = threadIdx.x;

    __shared__ __align__(16) float sA[C_DIM * C_DIM];
    __shared__ __align__(16) float sB[C_DIM * M_DIM];
    __shared__ __align__(16) float sPi[C_DIM];
    __shared__ __align__(16) unsigned char xs[2048];
    __shared__ float buf0[C_DIM * 256];   // L8 betas (SoA stride 256)
    __shared__ float buf1[C_DIM * 128];
    __shared__ float wsum[4];

    // ================= Phase A =================
    {   // xs gather: 512*256 = 131072 slots = 64 trees * 2048 (coalesced)
        int slot = bid * 256 + tid;
        int t = slot >> 11, i = slot & 2047;
        unsigned char v = 0;
        if (i < N1) v = (unsigned char)x[inv_map[t * N1 + i]];
        ((unsigned char*)ws)[XS_BYTE_OFF + slot] = v;
    }
    if (bid < G_DIM) {   // params: one g per block
        const int g = bid;
        float* pg = ws + g * PAR_STRIDE;
        {   // A: softmax over i within 16-lane segments
            int j = tid >> 4, i = tid & 15;
            float v = lA[(i * C_DIM + j) * G_DIM + g];
            float mx = v;
            #pragma unroll
            for (int m = 1; m < 16; m <<= 1) mx = fmaxf(mx, __shfl_xor(mx, m, 16));
            float e = __expf(v - mx);
            float s = e;
            #pragma unroll
            for (int m = 1; m < 16; m <<= 1) s += __shfl_xor(s, m, 16);
            pg[i * C_DIM + j] = e / s;
        }
        {   // B: softmax over m, row c, 4 symbols per lane
            int c = tid >> 4, l16 = tid & 15;
            float e0 = lB[(c * M_DIM + l16 +  0) * G_DIM + g];
            float e1 = lB[(c * M_DIM + l16 + 16) * G_DIM + g];
            float e2 = lB[(c * M_DIM + l16 + 32) * G_DIM + g];
            float e3 = lB[(c * M_DIM + l16 + 48) * G_DIM + g];
            float mx = fmaxf(fmaxf(e0, e1), fmaxf(e2, e3));
            #pragma unroll
            for (int m = 1; m < 16; m <<= 1) mx = fmaxf(mx, __shfl_xor(mx, m, 16));
            e0 = __expf(e0 - mx); e1 = __expf(e1 - mx);
            e2 = __expf(e2 - mx); e3 = __expf(e3 - mx);
            float s = e0 + e1 + e2 + e3;
            #pragma unroll
            for (int m = 1; m < 16; m <<= 1) s += __shfl_xor(s, m, 16);
            float inv = 1.f / s;
            pg[256 + c * M_DIM + l16 +  0] = e0 * inv;
            pg[256 + c * M_DIM + l16 + 16] = e1 * inv;
            pg[256 + c * M_DIM + l16 + 32] = e2 * inv;
            pg[256 + c * M_DIM + l16 + 48] = e3 * inv;
        }
        if (tid < C_DIM) {  // Pi
            float v = lPi[tid * G_DIM + g];
            float mx = v;
            #pragma unroll
            for (int m = 1; m < 16; m <<= 1) mx = fmaxf(mx, __shfl_xor(mx, m, 16));
            float e = __expf(v - mx);
            float s = e;
            #pragma unroll
            for (int m = 1; m < 16; m <<= 1) s += __shfl_xor(s, m, 16);
            pg[1280 + tid] = e / s;
        }
    }

    // ======= device barrier: distinct-word flags + fanned-out release =======
    {
        unsigned int* flags   = (unsigned int*)((char*)ws + BAR_BYTE_OFF);  // [512]
        unsigned int* release = flags + NBLOCKS;   // 64 words, stride 16 (64B)
        __syncthreads();                           // phase-A done in this block
        if (tid == 0) {
            __threadfence();                       // release phase-A writes
            __hip_atomic_store(&flags[bid], 1u, __ATOMIC_RELEASE,
                               __HIP_MEMORY_SCOPE_AGENT);
        }
        if (bid == 0) {
            // 256 threads sweep 512 distinct flags; poison == not-ready
            for (;;) {
                unsigned int a = __hip_atomic_load(&flags[tid],
                        __ATOMIC_RELAXED, __HIP_MEMORY_SCOPE_AGENT);
                unsigned int b = __hip_atomic_load(&flags[tid + 256],
                        __ATOMIC_RELAXED, __HIP_MEMORY_SCOPE_AGENT);
                bool ready = (a != POISON) && (b != POISON);
                if (__syncthreads_count(ready) == 256) break;
                __builtin_amdgcn_s_sleep(32);
            }
            __threadfence();
            if (tid < 64)   // fan-out: 64 release words on distinct lines
                __hip_atomic_store(&release[tid * 16], 1u, __ATOMIC_RELEASE,
                                   __HIP_MEMORY_SCOPE_AGENT);
        } else if (tid == 0) {
            unsigned int* myrel = &release[(bid & 63) * 16];  // 8 pollers/word
            while (__hip_atomic_load(myrel, __ATOMIC_ACQUIRE,
                                     __HIP_MEMORY_SCOPE_AGENT) == POISON)
                __builtin_amdgcn_s_sleep(16);
            __threadfence();                       // acquire others' writes
        }
        __syncthreads();
    }

    // ================= Phase B =================
    const int gh = bid >> 6;          // 0..7 -> g = gh, gh+8
    const int t  = bid & (T_TREES-1); // bid%8 == t%8 -> same-tree blocks share XCD

    // tree symbols: load once (2KB, coalesced)
    if (tid < 128)
        ((int4*)xs)[tid] =
            ((const int4*)((const unsigned char*)ws + XS_BYTE_OFF + t * 2048))[tid];

    for (int rep = 0; rep < 2; ++rep) {
        const int g = gh + rep * 8;
        {   // compact param loads for this g
            const float* pg = ws + g * PAR_STRIDE;
            ((float4*)sB)[tid] = ((const float4*)(pg + 256))[tid];
            if (tid < 64)  ((float4*)sA)[tid]  = ((const float4*)pg)[tid];
            if (tid < 4)   ((float4*)sPi)[tid] = ((const float4*)(pg + 1280))[tid];
        }
        __syncthreads();

        float ll = 0.f;

        // ---- fused leaves (L10) + L9 + L8: one L8 node per thread ----
        {
            const int idx = tid;
            const int p8  = 255 + idx;
            float s8[C_DIM];
            #pragma unroll
            for (int k = 0; k < C_DIM; ++k) s8[k] = 0.f;
            #pragma unroll
            for (int c9 = 0; c9 < 2; ++c9) {
                const int p9 = 2 * p8 + 1 + c9;
                float s9[C_DIM];
                #pragma unroll
                for (int k = 0; k < C_DIM; ++k) s9[k] = 0.f;
                #pragma unroll
                for (int cl = 0; cl < 2; ++cl) {
                    const int xv = xs[2 * p9 + 1 + cl];
                    float b[C_DIM]; float nu = 0.f;
                    #pragma unroll
                    for (int k = 0; k < C_DIM; ++k) {
                        b[k] = sPi[k] * sB[k * M_DIM + xv];
                        nu += b[k];
                    }
                    float inv = 0.5f / nu;
                    #pragma unroll
                    for (int k = 0; k < C_DIM; ++k) s9[k] += b[k] * inv;
                    ll += __logf(nu);
                }
                const int xv = xs[p9];
                float bp[C_DIM]; float nu = 0.f;
                #pragma unroll
                for (int i = 0; i < C_DIM; ++i) {
                    float ti = 0.f;
                    #pragma unroll
                    for (int j = 0; j < C_DIM; ++j) ti += sA[i * C_DIM + j] * s9[j];
                    bp[i] = ti * sB[i * M_DIM + xv];
                    nu += bp[i];
                }
                ll += __logf(nu);
                float inv = 0.5f / nu;
                #pragma unroll
                for (int k = 0; k < C_DIM; ++k) s8[k] += bp[k] * inv;
            }
            const int xv = xs[p8];
            float bp[C_DIM]; float nu = 0.f;
            #pragma unroll
            for (int i = 0; i < C_DIM; ++i) {
                float ti = 0.f;
                #pragma unroll
                for (int j = 0; j < C_DIM; ++j) ti += sA[i * C_DIM + j] * s8[j];
                bp[i] = ti * sB[i * M_DIM + xv];
                nu += bp[i];
            }
            ll += __logf(nu);
            float inv = 1.f / nu;
            #pragma unroll
            for (int k = 0; k < C_DIM; ++k) buf0[k * 256 + idx] = bp[k] * inv;
        }
        __syncthreads();

        // ---- L7: 128 nodes ----
        if (tid < 128) {
            const int idx = tid;
            float s[C_DIM];
            #pragma unroll
            for (int j = 0; j < C_DIM; ++j) {
                float2 cv = ((const float2*)(buf0 + j * 256))[idx];
                s[j] = 0.5f * (cv.x + cv.y);
            }
            const int xv = xs[127 + idx];
            float bp[C_DIM]; float nu = 0.f;
            #pragma unroll
            for (int i = 0; i < C_DIM; ++i) {
                float ti = 0.f;
                #pragma unroll
                for (int j = 0; j < C_DIM; ++j) ti += sA[i * C_DIM + j] * s[j];
                bp[i] = ti * sB[i * M_DIM + xv];
                nu += bp[i];
            }
            ll += __logf(nu);
            float inv = 1.f / nu;
            #pragma unroll
            for (int i = 0; i < C_DIM; ++i) buf1[i * 128 + idx] = bp[i] * inv;
        }
        __syncthreads();

        // ---- L6..L0 (64..1 nodes): wave 0 only, LDS fences not barriers ----
        if (tid < 64) {
            float* cur = buf1; int cs = 128;
            float* nxt = buf0; int ns = 256;
            for (int cnt2 = 64; cnt2 >= 1; cnt2 >>= 1) {
                if (tid < cnt2) {
                    const int idx = tid;
                    float s[C_DIM];
                    #pragma unroll
                    for (int j = 0; j < C_DIM; ++j) {
                        float a  = cur[j * cs + 2 * idx];
                        float b2 = cur[j * cs + 2 * idx + 1];
                        s[j] = 0.5f * (a + b2);
                    }
                    const int xv = xs[cnt2 - 1 + idx];
                    float bp[C_DIM]; float nu = 0.f;
                    #pragma unroll
                    for (int i = 0; i < C_DIM; ++i) {
                        float ti = 0.f;
                        #pragma unroll
                        for (int j = 0; j < C_DIM; ++j) ti += sA[i * C_DIM + j] * s[j];
                        bp[i] = ti * sB[i * M_DIM + xv];
                        nu += bp[i];
                    }
                    ll += __logf(nu);
                    float inv = 1.f / nu;
                    #pragma unroll
                    for (int i = 0; i < C_DIM; ++i) nxt[i * ns + idx] = bp[i] * inv;
                }
                asm volatile("s_waitcnt lgkmcnt(0)" ::: "memory");
                __builtin_amdgcn_wave_barrier();
                float* tp = cur; cur = nxt; nxt = tp;
                int ts = cs; cs = ns; ns = ts;
            }
        }

        // ---- reduce ll across block ----
        float v = ll;
        #pragma unroll
        for (int off = 32; off > 0; off >>= 1) v += __shfl_down(v, off, 64);
        if ((tid & 63) == 0) wsum[tid >> 6] = v;
        __syncthreads();
        if (tid == 0) out[t * G_DIM + g] = wsum[0] + wsum[1] + wsum[2] + wsum[3];
        __syncthreads();   // buffers/params reused next rep
    }
}

extern "C" void kernel_launch(void* const* d_in, const int* in_sizes, int n_in,
                              void* d_out, int out_size, void* d_ws, size_t ws_size,
                              hipStream_t stream) {
    const int*   x       = (const int*)d_in[0];
    const int*   inv_map = (const int*)d_in[6];
    const float* lA      = (const float*)d_in[7];
    const float* lB      = (const float*)d_in[8];
    const float* lPi     = (const float*)d_in[9];
    float* ws  = (float*)d_ws;
    float* out = (float*)d_out;

    htmm_fused<<<dim3(NBLOCKS), dim3(256), 0, stream>>>(
        x, inv_map, lA, lB, lPi, ws, out);
}

// Round 12
// 166.754 us; speedup vs baseline: 1.3983x; 1.2984x over previous
//
#include <hip/hip_runtime.h>

// UniformBottomUpHTMM: T=64 trees, depth 10 (N1=2047, heap layout), C=16,
// M=64, G=16. SINGLE kernel, 512 blocks, device barrier in which EVERY
// signal/poll is an atomic RMW (coherent-point guaranteed, per m20) --
// plain agent-scope atomic loads/stores can be served STALE from the
// non-coherent per-XCD L2 until eviction, which is the r8-r11 ~130us stall:
//   arrival: atomicExch(&flags[bid],1)   (512 distinct words)
//   sweep:   block 0 polls via atomicOr(&flags[i],0) (RMW read)
//   release: 64 words spaced 64B, atomicExch to set, atomicOr to poll
// Data visibility across the barrier via __threadfence (device scope).
// Phase A/B identical to r8/r11.

#define C_DIM 16
#define M_DIM 64
#define G_DIM 16
#define T_TREES 64
#define N1 2047

#define PAR_STRIDE 1536
#define XS_BYTE_OFF (G_DIM * PAR_STRIDE * 4)     // 98304
#define BAR_BYTE_OFF (512 * 1024)                // barrier region in d_ws
#define NBLOCKS 512

__global__ __launch_bounds__(256, 2) void htmm_fused(
    const int* __restrict__ x,
    const int* __restrict__ inv_map,
    const float* __restrict__ lA,
    const float* __restrict__ lB,
    const float* __restrict__ lPi,
    float* __restrict__ ws,
    float* __restrict__ out)
{
    const int bid = blockIdx.x;      // 512 blocks, all co-resident (cap 1024)
    const int tid = threadIdx.x;

    __shared__ __align__(16) float sA[C_DIM * C_DIM];
    __shared__ __align__(16) float sB[C_DIM * M_DIM];
    __shared__ __align__(16) float sPi[C_DIM];
    __shared__ __align__(16) unsigned char xs[2048];
    __shared__ float buf0[C_DIM * 256];   // L8 betas (SoA stride 256)
    __shared__ float buf1[C_DIM * 128];
    __shared__ float wsum[4];

    // ================= Phase A =================
    {   // xs gather: 512*256 = 131072 slots = 64 trees * 2048 (coalesced)
        int slot = bid * 256 + tid;
        int t = slot >> 11, i = slot & 2047;
        unsigned char v = 0;
        if (i < N1) v = (unsigned char)x[inv_map[t * N1 + i]];
        ((unsigned char*)ws)[XS_BYTE_OFF + slot] = v;
    }
    if (bid < G_DIM) {   // params: one g per block
        const int g = bid;
        float* pg = ws + g * PAR_STRIDE;
        {   // A: softmax over i within 16-lane segments
            int j = tid >> 4, i = tid & 15;
            float v = lA[(i * C_DIM + j) * G_DIM + g];
            float mx = v;
            #pragma unroll
            for (int m = 1; m < 16; m <<= 1) mx = fmaxf(mx, __shfl_xor(mx, m, 16));
            float e = __expf(v - mx);
            float s = e;
            #pragma unroll
            for (int m = 1; m < 16; m <<= 1) s += __shfl_xor(s, m, 16);
            pg[i * C_DIM + j] = e / s;
        }
        {   // B: softmax over m, row c, 4 symbols per lane
            int c = tid >> 4, l16 = tid & 15;
            float e0 = lB[(c * M_DIM + l16 +  0) * G_DIM + g];
            float e1 = lB[(c * M_DIM + l16 + 16) * G_DIM + g];
            float e2 = lB[(c * M_DIM + l16 + 32) * G_DIM + g];
            float e3 = lB[(c * M_DIM + l16 + 48) * G_DIM + g];
            float mx = fmaxf(fmaxf(e0, e1), fmaxf(e2, e3));
            #pragma unroll
            for (int m = 1; m < 16; m <<= 1) mx = fmaxf(mx, __shfl_xor(mx, m, 16));
            e0 = __expf(e0 - mx); e1 = __expf(e1 - mx);
            e2 = __expf(e2 - mx); e3 = __expf(e3 - mx);
            float s = e0 + e1 + e2 + e3;
            #pragma unroll
            for (int m = 1; m < 16; m <<= 1) s += __shfl_xor(s, m, 16);
            float inv = 1.f / s;
            pg[256 + c * M_DIM + l16 +  0] = e0 * inv;
            pg[256 + c * M_DIM + l16 + 16] = e1 * inv;
            pg[256 + c * M_DIM + l16 + 32] = e2 * inv;
            pg[256 + c * M_DIM + l16 + 48] = e3 * inv;
        }
        if (tid < C_DIM) {  // Pi
            float v = lPi[tid * G_DIM + g];
            float mx = v;
            #pragma unroll
            for (int m = 1; m < 16; m <<= 1) mx = fmaxf(mx, __shfl_xor(mx, m, 16));
            float e = __expf(v - mx);
            float s = e;
            #pragma unroll
            for (int m = 1; m < 16; m <<= 1) s += __shfl_xor(s, m, 16);
            pg[1280 + tid] = e / s;
        }
    }

    // ========== device barrier: ALL signals/polls are coherent RMWs ==========
    {
        unsigned int* flags   = (unsigned int*)((char*)ws + BAR_BYTE_OFF);  // [512]
        unsigned int* release = flags + NBLOCKS;   // 64 words, stride 16 (64B)
        __syncthreads();                           // phase-A done in this block
        if (tid == 0) {
            __threadfence();                       // release phase-A writes
            atomicExch(&flags[bid], 1u);           // coherent arrival
        }
        if (bid == 0) {
            // 256 threads sweep 512 distinct flags via RMW reads
            for (;;) {
                unsigned int a = atomicOr(&flags[tid], 0u);
                unsigned int b = atomicOr(&flags[tid + 256], 0u);
                bool ready = (a == 1u) && (b == 1u);
                if (__syncthreads_count(ready) == 256) break;
                __builtin_amdgcn_s_sleep(8);
            }
            __threadfence();
            if (tid < 64)   // fan-out: 64 release words on distinct lines
                atomicExch(&release[tid * 16], 1u);
        } else if (tid == 0) {
            unsigned int* myrel = &release[(bid & 63) * 16];  // 8 pollers/word
            while (atomicOr(myrel, 0u) != 1u)
                __builtin_amdgcn_s_sleep(8);
            __threadfence();                       // acquire others' writes
        }
        __syncthreads();
    }

    // ================= Phase B =================
    const int gh = bid >> 6;          // 0..7 -> g = gh, gh+8
    const int t  = bid & (T_TREES-1); // bid%8 == t%8 -> same-tree blocks share XCD

    // tree symbols: load once (2KB, coalesced)
    if (tid < 128)
        ((int4*)xs)[tid] =
            ((const int4*)((const unsigned char*)ws + XS_BYTE_OFF + t * 2048))[tid];

    for (int rep = 0; rep < 2; ++rep) {
        const int g = gh + rep * 8;
        {   // compact param loads for this g
            const float* pg = ws + g * PAR_STRIDE;
            ((float4*)sB)[tid] = ((const float4*)(pg + 256))[tid];
            if (tid < 64)  ((float4*)sA)[tid]  = ((const float4*)pg)[tid];
            if (tid < 4)   ((float4*)sPi)[tid] = ((const float4*)(pg + 1280))[tid];
        }
        __syncthreads();

        float ll = 0.f;

        // ---- fused leaves (L10) + L9 + L8: one L8 node per thread ----
        {
            const int idx = tid;
            const int p8  = 255 + idx;
            float s8[C_DIM];
            #pragma unroll
            for (int k = 0; k < C_DIM; ++k) s8[k] = 0.f;
            #pragma unroll
            for (int c9 = 0; c9 < 2; ++c9) {
                const int p9 = 2 * p8 + 1 + c9;
                float s9[C_DIM];
                #pragma unroll
                for (int k = 0; k < C_DIM; ++k) s9[k] = 0.f;
                #pragma unroll
                for (int cl = 0; cl < 2; ++cl) {
                    const int xv = xs[2 * p9 + 1 + cl];
                    float b[C_DIM]; float nu = 0.f;
                    #pragma unroll
                    for (int k = 0; k < C_DIM; ++k) {
                        b[k] = sPi[k] * sB[k * M_DIM + xv];
                        nu += b[k];
                    }
                    float inv = 0.5f / nu;
                    #pragma unroll
                    for (int k = 0; k < C_DIM; ++k) s9[k] += b[k] * inv;
                    ll += __logf(nu);
                }
                const int xv = xs[p9];
                float bp[C_DIM]; float nu = 0.f;
                #pragma unroll
                for (int i = 0; i < C_DIM; ++i) {
                    float ti = 0.f;
                    #pragma unroll
                    for (int j = 0; j < C_DIM; ++j) ti += sA[i * C_DIM + j] * s9[j];
                    bp[i] = ti * sB[i * M_DIM + xv];
                    nu += bp[i];
                }
                ll += __logf(nu);
                float inv = 0.5f / nu;
                #pragma unroll
                for (int k = 0; k < C_DIM; ++k) s8[k] += bp[k] * inv;
            }
            const int xv = xs[p8];
            float bp[C_DIM]; float nu = 0.f;
            #pragma unroll
            for (int i = 0; i < C_DIM; ++i) {
                float ti = 0.f;
                #pragma unroll
                for (int j = 0; j < C_DIM; ++j) ti += sA[i * C_DIM + j] * s8[j];
                bp[i] = ti * sB[i * M_DIM + xv];
                nu += bp[i];
            }
            ll += __logf(nu);
            float inv = 1.f / nu;
            #pragma unroll
            for (int k = 0; k < C_DIM; ++k) buf0[k * 256 + idx] = bp[k] * inv;
        }
        __syncthreads();

        // ---- L7: 128 nodes ----
        if (tid < 128) {
            const int idx = tid;
            float s[C_DIM];
            #pragma unroll
            for (int j = 0; j < C_DIM; ++j) {
                float2 cv = ((const float2*)(buf0 + j * 256))[idx];
                s[j] = 0.5f * (cv.x + cv.y);
            }
            const int xv = xs[127 + idx];
            float bp[C_DIM]; float nu = 0.f;
            #pragma unroll
            for (int i = 0; i < C_DIM; ++i) {
                float ti = 0.f;
                #pragma unroll
                for (int j = 0; j < C_DIM; ++j) ti += sA[i * C_DIM + j] * s[j];
                bp[i] = ti * sB[i * M_DIM + xv];
                nu += bp[i];
            }
            ll += __logf(nu);
            float inv = 1.f / nu;
            #pragma unroll
            for (int i = 0; i < C_DIM; ++i) buf1[i * 128 + idx] = bp[i] * inv;
        }
        __syncthreads();

        // ---- L6..L0 (64..1 nodes): wave 0 only, LDS fences not barriers ----
        if (tid < 64) {
            float* cur = buf1; int cs = 128;
            float* nxt = buf0; int ns = 256;
            for (int cnt2 = 64; cnt2 >= 1; cnt2 >>= 1) {
                if (tid < cnt2) {
                    const int idx = tid;
                    float s[C_DIM];
                    #pragma unroll
                    for (int j = 0; j < C_DIM; ++j) {
                        float a  = cur[j * cs + 2 * idx];
                        float b2 = cur[j * cs + 2 * idx + 1];
                        s[j] = 0.5f * (a + b2);
                    }
                    const int xv = xs[cnt2 - 1 + idx];
                    float bp[C_DIM]; float nu = 0.f;
                    #pragma unroll
                    for (int i = 0; i < C_DIM; ++i) {
                        float ti = 0.f;
                        #pragma unroll
                        for (int j = 0; j < C_DIM; ++j) ti += sA[i * C_DIM + j] * s[j];
                        bp[i] = ti * sB[i * M_DIM + xv];
                        nu += bp[i];
                    }
                    ll += __logf(nu);
                    float inv = 1.f / nu;
                    #pragma unroll
                    for (int i = 0; i < C_DIM; ++i) nxt[i * ns + idx] = bp[i] * inv;
                }
                asm volatile("s_waitcnt lgkmcnt(0)" ::: "memory");
                __builtin_amdgcn_wave_barrier();
                float* tp = cur; cur = nxt; nxt = tp;
                int ts = cs; cs = ns; ns = ts;
            }
        }

        // ---- reduce ll across block ----
        float v = ll;
        #pragma unroll
        for (int off = 32; off > 0; off >>= 1) v += __shfl_down(v, off, 64);
        if ((tid & 63) == 0) wsum[tid >> 6] = v;
        __syncthreads();
        if (tid == 0) out[t * G_DIM + g] = wsum[0] + wsum[1] + wsum[2] + wsum[3];
        __syncthreads();   // buffers/params reused next rep
    }
}

extern "C" void kernel_launch(void* const* d_in, const int* in_sizes, int n_in,
                              void* d_out, int out_size, void* d_ws, size_t ws_size,
                              hipStream_t stream) {
    const int*   x       = (const int*)d_in[0];
    const int*   inv_map = (const int*)d_in[6];
    const float* lA      = (const float*)d_in[7];
    const float* lB      = (const float*)d_in[8];
    const float* lPi     = (const float*)d_in[9];
    float* ws  = (float*)d_ws;
    float* out = (float*)d_out;

    htmm_fused<<<dim3(NBLOCKS), dim3(256), 0, stream>>>(
        x, inv_map, lA, lB, lPi, ws, out);
}